// Round 15
// baseline (277.415 us; speedup 1.0000x reference)
//
#include <hip/hip_runtime.h>
#include <cmath>

// ---------------- problem constants ----------------
#define NLAYERS 100      // hidden layers (scan)
#define DIN     64       // input features
#define WDIM    100      // hidden width
#define NTT     8        // total n tiles (128 cols incl bias col 112 + pads)
#define NTW     2        // n tiles per wave (wave w owns nt = 2w, 2w+1)
#define RT      4        // row tiles per block -> 64 rows
#define ROWS    64
#define PSTR    136      // f16 plane row stride (272 B: b128-aligned)
#define RTPLANE (16 * PSTR)      // one 16-row plane, halves (2176)
#define BUF     (RT * RTPLANE)   // one h buffer (64 rows), halves (8704)

typedef _Float16 half8 __attribute__((ext_vector_type(8)));
typedef _Float16 half2v __attribute__((ext_vector_type(2)));
typedef __fp16   fp16x2 __attribute__((ext_vector_type(2)));
typedef float    f32x4 __attribute__((ext_vector_type(4)));

// ---------------- workspace layout ----------------
// wsh: [l][ks][nt8][lane][8] — frag stride 512 halves (1024 B), imm-offset loads.
// Frag (ks,nt), lane(q,l15), elem j = W[k=ks*32+q*8+j][n=nt*16+l15], with:
//   k==112 && n<100  -> layer bias   (h col 112 == 1.0)
//   k==112 && n==112 -> 1.0          (bias col self-sustains through the MFMA)
#define WSH_LAYER_HALVES (4 * NTT * 64 * 8)              // 16384
#define WSH_HALVES       (NLAYERS * WSH_LAYER_HALVES)    // 1,638,400
#define W0_HALVES        (2 * NTT * 64 * 8)              // 8192 (input layer, K=64)
#define BPAD_FLOATS      128                             // b_in padded, col112 = 1.0
#define OFF_BPAD_B       ((WSH_HALVES + W0_HALVES) * 2)
#define OFF_WOUT_B       (OFF_BPAD_B + BPAD_FLOATS * 4)
#define WOUT_FLOATS      128
#define TOTAL_PREP       (WSH_HALVES + W0_HALVES + BPAD_FLOATS + WOUT_FLOATS)

__global__ void actor_prep(const float* __restrict__ Win, const float* __restrict__ bin,
                           const float* __restrict__ Ws,  const float* __restrict__ bs,
                           const float* __restrict__ Wout,
                           _Float16* __restrict__ wsh, _Float16* __restrict__ w0sh,
                           float* __restrict__ bpad, float* __restrict__ woutp) {
    int t = blockIdx.x * 256 + threadIdx.x;
    if (t < WSH_HALVES) {                       // hidden-layer weights
        int j    = t & 7;
        int lane = (t >> 3) & 63;
        int fid  = t >> 9;                      // (l*4 + ks)*8 + nt
        int nt   = fid & 7;
        int r2   = fid >> 3;
        int ks   = r2 & 3;
        int l    = r2 >> 2;
        int k = ks * 32 + (lane >> 4) * 8 + j;
        int n = nt * 16 + (lane & 15);
        float v = 0.f;
        if (k < WDIM && n < WDIM)            v = Ws[(l * WDIM + k) * WDIM + n];
        else if (k == 112 && n < WDIM)       v = bs[l * WDIM + n];   // bias row
        else if (k == 112 && n == 112)       v = 1.0f;               // keep bias col alive
        wsh[t] = (_Float16)v;
        return;
    }
    int t2 = t - WSH_HALVES;
    if (t2 < W0_HALVES) {                       // input layer weights (K=64)
        int j    = t2 & 7;
        int lane = (t2 >> 3) & 63;
        int fid  = t2 >> 9;                     // ks*8 + nt
        int nt   = fid & 7;
        int ks   = fid >> 3;
        int k = ks * 32 + (lane >> 4) * 8 + j;
        int n = nt * 16 + (lane & 15);
        float v = (k < DIN && n < WDIM) ? Win[k * WDIM + n] : 0.f;
        w0sh[t2] = (_Float16)v;
        return;
    }
    int t3 = t2 - W0_HALVES;
    if (t3 < BPAD_FLOATS) {                     // padded b_in; col 112 = 1.0 seeds bias col
        float v = (t3 < WDIM) ? bin[t3] : (t3 == 112 ? 1.0f : 0.f);
        bpad[t3] = v;
        return;
    }
    int t4 = t3 - BPAD_FLOATS;
    if (t4 < WOUT_FLOATS) woutp[t4] = (t4 < WDIM) ? Wout[t4] : 0.f;
}

// split fp32 -> hi/lo fp16 (layer-0 input only: keep input fidelity)
__device__ __forceinline__ void split8(const float* __restrict__ p, half8& hi, half8& lo) {
    f32x4 u0 = *(const f32x4*)p;
    f32x4 u1 = *(const f32x4*)(p + 4);
    float v[8] = {u0[0], u0[1], u0[2], u0[3], u1[0], u1[1], u1[2], u1[3]};
#pragma unroll
    for (int e = 0; e < 8; e += 2) {
        fp16x2 h = __builtin_amdgcn_cvt_pkrtz(v[e], v[e + 1]);
        float r0 = v[e]     - (float)h[0];
        float r1 = v[e + 1] - (float)h[1];
        fp16x2 l = __builtin_amdgcn_cvt_pkrtz(r0, r1);
        hi[e] = (_Float16)h[0]; hi[e + 1] = (_Float16)h[1];
        lo[e] = (_Float16)l[0]; lo[e + 1] = (_Float16)l[1];
    }
}

// epilogue one C-tile: RNE f16 cvt, packed-f16 leaky, single b64 store
__device__ __forceinline__ void ep_tile(const f32x4 a, _Float16* __restrict__ d) {
    half2v p01, p23;
    p01[0] = (_Float16)a[0]; p01[1] = (_Float16)a[1];
    p23[0] = (_Float16)a[2]; p23[1] = (_Float16)a[3];
    const half2v slope = {(_Float16)0.01f, (_Float16)0.01f};
    p01 = __builtin_elementwise_max(p01, p01 * slope);
    p23 = __builtin_elementwise_max(p23, p23 * slope);
    uint2 w;
    w.x = __builtin_bit_cast(unsigned, p01);
    w.y = __builtin_bit_cast(unsigned, p23);
    *reinterpret_cast<uint2*>(d) = w;                    // ds_write_b64
}

// ============================================================
// Main: 256-thread blocks (4 waves), 64 rows. N-SPLIT 4 ways: wave w
// owns output tiles nt = {2w, 2w+1} (8 KB weights/layer/wave). r15 vs
// r14: per-CU aggregate demand on every pipe is IDENTICAL (4 blk x 4
// waves x 8 KB = r14's 4 x 2 x 16 KB), but TLP doubles to 4 waves/SIMD
// — the r14 post-mortem showed no pipe above 50% with the wall set by
// imperfect 2-wave overlap. __launch_bounds__(256,4) caps VGPR at 128
// so 4 blocks/CU stay resident.
// h (f16 hi-only; absmax 0.094, r8-r14) in LDS, double-buffered by
// layer parity; one barrier/layer. Within a wave, 4 row-tiles give
// r10-style overlap: epi(L,rt-1) interleaves into mfma(L,rt). Bias col
// 112 self-sustains (W[112][112]=1.0; wave3's tile-7 epi rewrites it).
// Heads: per-wave partial dot, combined through LDS.
// ============================================================
__global__ __launch_bounds__(256, 4)
void actor_main(const float* __restrict__ x,
                const _Float16* __restrict__ wsh,
                const _Float16* __restrict__ w0sh,
                const float* __restrict__ bpad,
                const float* __restrict__ woutp,
                const float* __restrict__ bout,
                float* __restrict__ out) {
    __shared__ _Float16 hp[2 * BUF];     // two 64-row h buffers (layer parity)
    const int lane = threadIdx.x & 63;
    const int wid  = threadIdx.x >> 6;   // 0..3: owns nt {2w, 2w+1}
    const int q = lane >> 4, l15 = lane & 15;
    const int rowbase = blockIdx.x * ROWS;
    const int ntb = wid * NTW;           // tile base

    f32x4 acc[RT][NTW];
    half8 wb[4][NTW];                    // my eighth-layer of W frags, register-resident
    const f32x4 zero4 = {0.f, 0.f, 0.f, 0.f};

    // ---- input layer (K=64): acc init = bpad (col112 -> 1.0 seed), 2 ks steps ----
#pragma unroll
    for (int ks = 0; ks < 2; ++ks)
#pragma unroll
        for (int ntl = 0; ntl < NTW; ++ntl)
            wb[ks][ntl] = *(const half8*)(w0sh + (ks * NTT + ntb + ntl) * 512 + lane * 8);
#pragma unroll
    for (int rt = 0; rt < RT; ++rt)
#pragma unroll
        for (int ntl = 0; ntl < NTW; ++ntl)
            acc[rt][ntl] = *(const f32x4*)(bpad + (ntb + ntl) * 16 + q * 4);
#pragma unroll
    for (int rt = 0; rt < RT; ++rt) {
        const float* xr = x + (rowbase + rt * 16 + l15) * DIN;
#pragma unroll
        for (int ks = 0; ks < 2; ++ks) {
            half8 xhi, xlo;
            split8(xr + ks * 32 + q * 8, xhi, xlo);
#pragma unroll
            for (int ntl = 0; ntl < NTW; ++ntl) {
                acc[rt][ntl] = __builtin_amdgcn_mfma_f32_16x16x32_f16(wb[ks][ntl], xhi, acc[rt][ntl], 0, 0, 0);
                acc[rt][ntl] = __builtin_amdgcn_mfma_f32_16x16x32_f16(wb[ks][ntl], xlo, acc[rt][ntl], 0, 0, 0);
            }
        }
    }
    // epi0 -> buffer 0 (all my tiles, all rts); prefetch W(0)
#pragma unroll
    for (int rt = 0; rt < RT; ++rt)
#pragma unroll
        for (int ntl = 0; ntl < NTW; ++ntl)
            ep_tile(acc[rt][ntl], hp + rt * RTPLANE + l15 * PSTR + (ntb + ntl) * 16 + q * 4);
#pragma unroll
    for (int ks = 0; ks < 4; ++ks)
#pragma unroll
        for (int ntl = 0; ntl < NTW; ++ntl)
            wb[ks][ntl] = *(const half8*)(wsh + (ks * NTT + ntb + ntl) * 512 + lane * 8);
    __syncthreads();

    // ---------------- 100 hidden layers ----------------
    // layer l: reads buf[l&1] (h of layer l-1), writes buf[(l+1)&1]
#pragma unroll 1
    for (int l = 0; l < NLAYERS; ++l) {
        const _Float16* rb = hp + (l & 1) * BUF;
        _Float16* wbf = hp + ((l + 1) & 1) * BUF;
        const _Float16* wn = wsh + (l < NLAYERS - 1 ? l + 1 : l) * WSH_LAYER_HALVES;

#pragma unroll
        for (int rt = 0; rt < RT; ++rt) {
            // hoisted B-frag reads (before any epi write queues behind them)
            half8 bh[4];
#pragma unroll
            for (int ks = 0; ks < 4; ++ks)
                bh[ks] = *(const half8*)(rb + rt * RTPLANE + l15 * PSTR + ks * 32 + q * 8);
            _Float16* dprev = wbf + (rt - 1) * RTPLANE + l15 * PSTR + q * 4;
#pragma unroll
            for (int ks = 0; ks < 4; ++ks) {
#pragma unroll
                for (int ntl = 0; ntl < NTW; ++ntl)
                    acc[rt][ntl] = __builtin_amdgcn_mfma_f32_16x16x32_f16(
                        wb[ks][ntl], bh[ks], (ks == 0 ? zero4 : acc[rt][ntl]), 0, 0, 0);
                // interleave: epi tiles of rt-1 (independent of this mfma); 2 cells over 4 ks slots
                if (rt >= 1 && ks < NTW)
                    ep_tile(acc[rt - 1][ks], dprev + (ntb + ks) * 16);
                // during the last rt, wb[ks] is dead after its mfma: refill with W(L+1)
                if (rt == RT - 1) {
#pragma unroll
                    for (int ntl = 0; ntl < NTW; ++ntl)
                        wb[ks][ntl] = *(const half8*)(wn + (ks * NTT + ntb + ntl) * 512 + lane * 8);
                }
            }
        }
        // tail: epi of rt3, then layer barrier
        _Float16* dlast = wbf + (RT - 1) * RTPLANE + l15 * PSTR + q * 4;
#pragma unroll
        for (int ntl = 0; ntl < NTW; ++ntl)
            ep_tile(acc[RT - 1][ntl], dlast + (ntb + ntl) * 16);
        __syncthreads();
    }
    // acc[rt][ntl] = pre-activation of layer 99 for my cols (preserved in regs)

    // ---------------- heads: leaky + dot(W_out) over my cols, combine via LDS ----------------
    float part[RT];
#pragma unroll
    for (int rt = 0; rt < RT; ++rt) {
        float s = 0.f;
#pragma unroll
        for (int ntl = 0; ntl < NTW; ++ntl) {
            f32x4 w4 = *(const f32x4*)(woutp + (ntb + ntl) * 16 + q * 4);
#pragma unroll
            for (int r = 0; r < 4; ++r) {
                float a = acc[rt][ntl][r];
                float v = fmaxf(a, 0.01f * a);
                s += v * w4[r];
            }
        }
        s += __shfl_xor(s, 16);
        s += __shfl_xor(s, 32);
        part[rt] = s;
    }
    float* red = (float*)hp;             // 256 floats of scratch (h is dead)
    __syncthreads();                     // ensure all layer reads done before overwrite
#pragma unroll
    for (int rt = 0; rt < RT; ++rt)
        if (q == 0) red[wid * 64 + rt * 16 + l15] = part[rt];
    __syncthreads();
    {
        const int r = threadIdx.x;
        if (r < 64) {
            float tot = red[r] + red[64 + r] + red[128 + r] + red[192 + r] + bout[0];
            out[rowbase + r] = tanhf(tot) * 4.5f + 5.5f;   // (tanh+1)/2*9 + 1
        }
    }
}

extern "C" void kernel_launch(void* const* d_in, const int* in_sizes, int n_in,
                              void* d_out, int out_size, void* d_ws, size_t ws_size,
                              hipStream_t stream) {
    const float* x    = (const float*)d_in[0];
    const float* Win  = (const float*)d_in[1];
    const float* bin  = (const float*)d_in[2];
    const float* Ws   = (const float*)d_in[3];
    const float* bs   = (const float*)d_in[4];
    const float* Wout = (const float*)d_in[5];
    const float* bout = (const float*)d_in[6];
    float* out = (float*)d_out;

    char* ws = (char*)d_ws;
    _Float16* wsh  = (_Float16*)ws;
    _Float16* w0sh = wsh + WSH_HALVES;
    float* bpad  = (float*)(ws + OFF_BPAD_B);
    float* woutp = (float*)(ws + OFF_WOUT_B);

    hipLaunchKernelGGL(actor_prep, dim3((TOTAL_PREP + 255) / 256), dim3(256), 0, stream,
                       Win, bin, Ws, bs, Wout, wsh, w0sh, bpad, woutp);

    const int nrows = in_sizes[0] / DIN;   // 65536
    hipLaunchKernelGGL(actor_main, dim3(nrows / ROWS), dim3(256), 0, stream,
                       x, wsh, w0sh, bpad, woutp, bout, out);
}

// Round 16
// 264.783 us; speedup vs baseline: 1.0477x; 1.0477x over previous
//
#include <hip/hip_runtime.h>
#include <cmath>

// ---------------- problem constants ----------------
#define NLAYERS 100      // hidden layers (scan)
#define DIN     64       // input features
#define WDIM    100      // hidden width
#define NTT     4        // 4 n-tiles of 32 (128 neuron cols; bias col = 100)
#define NTW     2        // n-tiles per wave (wave w owns nt = 2w, 2w+1)
#define RT      2        // two 32-row tiles -> 64 rows per block
#define ROWS    64
#define KS      7        // 7 k-steps of 16 -> K=112 (useful 101; cols 112+ never read)
#define PSTR    136      // f16 h row stride (272 B, b128-aligned; cols up to 127 writable)
#define BUF     (64 * PSTR)   // one 64-row h buffer in halves

typedef _Float16 half8  __attribute__((ext_vector_type(8)));
typedef _Float16 half2v __attribute__((ext_vector_type(2)));
typedef __fp16   fp16x2 __attribute__((ext_vector_type(2)));
typedef float    f32x4  __attribute__((ext_vector_type(4)));
typedef float    f32x16 __attribute__((ext_vector_type(16)));

// ---------------- workspace layout ----------------
// wsh: [l][ks7][nt4][lane][8] — frag stride 512 halves (1024 B).
// A-frag (32x32x16, operand-swapped W^T): lane m=lane&31 -> neuron
// n = nt*32 + (lane&31); elem j -> k = ks*16 + (lane>>5)*8 + j.
//   k<100 && n<100   -> Ws[l][k][n]
//   k==100 && n<100  -> bs[l][n]      (bias row vs h col 100 == 1.0)
//   k==100 && n==100 -> 1.0           (bias col self-sustains)
#define WSH_LAYER_HALVES (KS * NTT * 64 * 8)             // 14336
#define WSH_HALVES       (NLAYERS * WSH_LAYER_HALVES)    // 1,433,600
#define W0_HALVES        (4 * NTT * 64 * 8)              // 8192 (input, K=64 = 4 ks)
#define BPAD_FLOATS      128                             // b_in padded; col 100 = 1.0
#define OFF_BPAD_B       ((WSH_HALVES + W0_HALVES) * 2)
#define OFF_WOUT_B       (OFF_BPAD_B + BPAD_FLOATS * 4)
#define WOUT_FLOATS      128
#define TOTAL_PREP       (WSH_HALVES + W0_HALVES + BPAD_FLOATS + WOUT_FLOATS)

__global__ void actor_prep(const float* __restrict__ Win, const float* __restrict__ bin,
                           const float* __restrict__ Ws,  const float* __restrict__ bs,
                           const float* __restrict__ Wout,
                           _Float16* __restrict__ wsh, _Float16* __restrict__ w0sh,
                           float* __restrict__ bpad, float* __restrict__ woutp) {
    int t = blockIdx.x * 256 + threadIdx.x;
    if (t < WSH_HALVES) {                       // hidden-layer weights
        int j    = t & 7;
        int lane = (t >> 3) & 63;
        int fid  = t >> 9;                      // (l*7 + ks)*4 + nt
        int nt   = fid & 3;
        int r2   = fid >> 2;
        int ks   = r2 % 7;
        int l    = r2 / 7;
        int k = ks * 16 + (lane >> 5) * 8 + j;
        int n = nt * 32 + (lane & 31);
        float v = 0.f;
        if (k < WDIM && n < WDIM)            v = Ws[(l * WDIM + k) * WDIM + n];
        else if (k == 100 && n < WDIM)       v = bs[l * WDIM + n];   // bias row
        else if (k == 100 && n == 100)       v = 1.0f;               // keep bias col alive
        wsh[t] = (_Float16)v;
        return;
    }
    int t2 = t - WSH_HALVES;
    if (t2 < W0_HALVES) {                       // input layer (K=64)
        int j    = t2 & 7;
        int lane = (t2 >> 3) & 63;
        int fid  = t2 >> 9;                     // ks*4 + nt
        int nt   = fid & 3;
        int ks   = fid >> 2;
        int k = ks * 16 + (lane >> 5) * 8 + j;  // < 64
        int n = nt * 32 + (lane & 31);
        float v = (n < WDIM) ? Win[k * WDIM + n] : 0.f;
        w0sh[t2] = (_Float16)v;
        return;
    }
    int t3 = t2 - W0_HALVES;
    if (t3 < BPAD_FLOATS) {                     // padded b_in; col 100 = 1.0 seed
        float v = (t3 < WDIM) ? bin[t3] : (t3 == 100 ? 1.0f : 0.f);
        bpad[t3] = v;
        return;
    }
    int t4 = t3 - BPAD_FLOATS;
    if (t4 < WOUT_FLOATS) woutp[t4] = (t4 < WDIM) ? Wout[t4] : 0.f;
}

// split fp32 -> hi/lo fp16 (layer-0 input only: keep input fidelity)
__device__ __forceinline__ void split8(const float* __restrict__ p, half8& hi, half8& lo) {
    f32x4 u0 = *(const f32x4*)p;
    f32x4 u1 = *(const f32x4*)(p + 4);
    float v[8] = {u0[0], u0[1], u0[2], u0[3], u1[0], u1[1], u1[2], u1[3]};
#pragma unroll
    for (int e = 0; e < 8; e += 2) {
        fp16x2 h = __builtin_amdgcn_cvt_pkrtz(v[e], v[e + 1]);
        float r0 = v[e]     - (float)h[0];
        float r1 = v[e + 1] - (float)h[1];
        fp16x2 l = __builtin_amdgcn_cvt_pkrtz(r0, r1);
        hi[e] = (_Float16)h[0]; hi[e + 1] = (_Float16)h[1];
        lo[e] = (_Float16)l[0]; lo[e + 1] = (_Float16)l[1];
    }
}

// epilogue one QUAD (4 contiguous neurons = regs 4qd..4qd+3 of a 32x32 C):
// RNE f16 cvt, packed-f16 leaky, one b64 store
__device__ __forceinline__ void ep_quad(const f32x16 a, int qd, _Float16* __restrict__ d) {
    half2v p01, p23;
    p01[0] = (_Float16)a[4 * qd + 0]; p01[1] = (_Float16)a[4 * qd + 1];
    p23[0] = (_Float16)a[4 * qd + 2]; p23[1] = (_Float16)a[4 * qd + 3];
    const half2v slope = {(_Float16)0.01f, (_Float16)0.01f};
    p01 = __builtin_elementwise_max(p01, p01 * slope);
    p23 = __builtin_elementwise_max(p23, p23 * slope);
    uint2 w;
    w.x = __builtin_bit_cast(unsigned, p01);
    w.y = __builtin_bit_cast(unsigned, p23);
    *reinterpret_cast<uint2*>(d) = w;
}

// ============================================================
// Main: 128-thread blocks (2 waves), 64 rows, 32x32x16 MFMA.
// r16 vs r14: (1) 32x32 shape = 2495 vs 2075 TF (m119/m06): ~17% less
// MFMA-pipe time at equal FLOP, half the MFMA instructions; (2) K=112
// (7x16) instead of 128: bias moved to col 100, cutting the all-pad
// 4th k-step — MFMA/SIMD/layer 2483 -> 1809 cyc.
// C/D layout (HW-verified m74/m101): col(batch)=lane&31,
// row(neuron)=(reg&3)+8*(reg>>2)+4*(lane>>5) -> epi = 4 quad b64 writes.
// N-split: wave w owns nt {2w,2w+1}. h in LDS double-buffered by layer
// parity, 1 barrier/layer. 4 chunks (rt,ntl) per layer; chunk c's mfma
// stream hides chunk c-1's epi; W(L+1) prefetch hides in chunks 2-3.
// HI-ONLY f16 activations (absmax 0.094, r8-r15).
// ============================================================
__global__ __launch_bounds__(128, 2)
void actor_main(const float* __restrict__ x,
                const _Float16* __restrict__ wsh,
                const _Float16* __restrict__ w0sh,
                const float* __restrict__ bpad,
                const float* __restrict__ woutp,
                const float* __restrict__ bout,
                float* __restrict__ out) {
    __shared__ _Float16 hp[2 * BUF];     // two 64-row h buffers (layer parity)
    const int lane = threadIdx.x & 63;
    const int wid  = threadIdx.x >> 6;   // 0,1: owns nt {2w, 2w+1}
    const int g = lane >> 5, b31 = lane & 31;
    const int rowbase = blockIdx.x * ROWS;
    const int ntb = wid * NTW;

    f32x16 acc[RT][NTW];
    half8 wb[KS][NTW];                   // my W frags for the whole layer
    const f32x16 zero16 = {0,0,0,0, 0,0,0,0, 0,0,0,0, 0,0,0,0};

    // ---- input layer (K=64 = 4 k-steps of 16) ----
    half8 w0[4][NTW];
#pragma unroll
    for (int ks = 0; ks < 4; ++ks)
#pragma unroll
        for (int ntl = 0; ntl < NTW; ++ntl)
            w0[ks][ntl] = *(const half8*)(w0sh + (ks * NTT + ntb + ntl) * 512 + lane * 8);
    // acc init = bpad at this lane's 16 neuron rows (4 quads)
#pragma unroll
    for (int rt = 0; rt < RT; ++rt)
#pragma unroll
        for (int ntl = 0; ntl < NTW; ++ntl)
#pragma unroll
            for (int qd = 0; qd < 4; ++qd) {
                f32x4 tq = *(const f32x4*)(bpad + (ntb + ntl) * 32 + 8 * qd + 4 * g);
#pragma unroll
                for (int r = 0; r < 4; ++r) acc[rt][ntl][4 * qd + r] = tq[r];
            }
#pragma unroll
    for (int rt = 0; rt < RT; ++rt) {
        const float* xr = x + (rowbase + rt * 32 + b31) * DIN;
#pragma unroll
        for (int ks = 0; ks < 4; ++ks) {
            half8 xhi, xlo;
            split8(xr + ks * 16 + g * 8, xhi, xlo);
#pragma unroll
            for (int ntl = 0; ntl < NTW; ++ntl) {
                acc[rt][ntl] = __builtin_amdgcn_mfma_f32_32x32x16_f16(w0[ks][ntl], xhi, acc[rt][ntl], 0, 0, 0);
                acc[rt][ntl] = __builtin_amdgcn_mfma_f32_32x32x16_f16(w0[ks][ntl], xlo, acc[rt][ntl], 0, 0, 0);
            }
        }
    }
    // epi0 -> buffer 0; prefetch W(0)
#pragma unroll
    for (int rt = 0; rt < RT; ++rt)
#pragma unroll
        for (int ntl = 0; ntl < NTW; ++ntl) {
            _Float16* d = hp + (rt * 32 + b31) * PSTR + (ntb + ntl) * 32 + 4 * g;
#pragma unroll
            for (int qd = 0; qd < 4; ++qd) ep_quad(acc[rt][ntl], qd, d + 8 * qd);
        }
#pragma unroll
    for (int ks = 0; ks < KS; ++ks)
#pragma unroll
        for (int ntl = 0; ntl < NTW; ++ntl)
            wb[ks][ntl] = *(const half8*)(wsh + (ks * NTT + ntb + ntl) * 512 + lane * 8);
    __syncthreads();

    // ---------------- 100 hidden layers ----------------
    // layer l: reads buf[l&1] (h of l-1), writes buf[(l+1)&1]
#pragma unroll 1
    for (int l = 0; l < NLAYERS; ++l) {
        const _Float16* rb = hp + (l & 1) * BUF;
        _Float16* wbf = hp + ((l + 1) & 1) * BUF;
        const _Float16* wn = wsh + (l < NLAYERS - 1 ? l + 1 : l) * WSH_LAYER_HALVES;
        half8 bh[KS];

#pragma unroll
        for (int c = 0; c < 4; ++c) {            // chunk = (rt = c>>1, ntl = c&1)
            const int rt = c >> 1, ntl = c & 1;
            if (ntl == 0) {                      // hoist this rt's B-frag reads
#pragma unroll
                for (int ks = 0; ks < KS; ++ks)
                    bh[ks] = *(const half8*)(rb + (rt * 32 + b31) * PSTR + ks * 16 + g * 8);
            }
            const int prt = (c - 1) >> 1, pntl = (c - 1) & 1;
            _Float16* dp = wbf + (prt * 32 + b31) * PSTR + (ntb + pntl) * 32 + 4 * g;
#pragma unroll
            for (int ks = 0; ks < KS; ++ks) {
                acc[rt][ntl] = __builtin_amdgcn_mfma_f32_32x32x16_f16(
                    wb[ks][ntl], bh[ks], (ks == 0 ? zero16 : acc[rt][ntl]), 0, 0, 0);
                if (c > 0 && ks < 4)             // hide prev chunk's epi (4 quads)
                    ep_quad(acc[prt][pntl], ks, dp + 8 * ks);
                if (c == 2)                      // wb[ks][0] dead: refill W(L+1)
                    wb[ks][0] = *(const half8*)(wn + (ks * NTT + ntb + 0) * 512 + lane * 8);
                if (c == 3)                      // wb[ks][1] dead: refill W(L+1)
                    wb[ks][1] = *(const half8*)(wn + (ks * NTT + ntb + 1) * 512 + lane * 8);
            }
        }
        // tail: epi of chunk 3, then layer barrier
        {
            _Float16* dl = wbf + (32 + b31) * PSTR + (ntb + 1) * 32 + 4 * g;
#pragma unroll
            for (int qd = 0; qd < 4; ++qd) ep_quad(acc[1][1], qd, dl + 8 * qd);
        }
        __syncthreads();
    }
    // acc[rt][ntl] = pre-activation of layer 99 for my neurons (in regs)

    // ---------------- heads: leaky + dot(W_out), combine via LDS ----------------
    float part[RT];
#pragma unroll
    for (int rt = 0; rt < RT; ++rt) {
        float s = 0.f;
#pragma unroll
        for (int ntl = 0; ntl < NTW; ++ntl)
#pragma unroll
            for (int qd = 0; qd < 4; ++qd) {
                f32x4 w4 = *(const f32x4*)(woutp + (ntb + ntl) * 32 + 8 * qd + 4 * g);
#pragma unroll
                for (int r = 0; r < 4; ++r) {
                    float a = acc[rt][ntl][4 * qd + r];
                    float v = fmaxf(a, 0.01f * a);
                    s += v * w4[r];
                }
            }
        s += __shfl_xor(s, 32);                  // combine the two k-groups (same batch)
        part[rt] = s;
    }
    float* red = (float*)hp;                     // scratch (final barrier already passed)
#pragma unroll
    for (int rt = 0; rt < RT; ++rt)
        if (lane < 32) red[wid * 64 + rt * 32 + b31] = part[rt];
    __syncthreads();
    {
        const int r = threadIdx.x;
        if (r < 64) {
            float tot = red[r] + red[64 + r] + bout[0];
            out[rowbase + r] = tanhf(tot) * 4.5f + 5.5f;   // (tanh+1)/2*9 + 1
        }
    }
}

extern "C" void kernel_launch(void* const* d_in, const int* in_sizes, int n_in,
                              void* d_out, int out_size, void* d_ws, size_t ws_size,
                              hipStream_t stream) {
    const float* x    = (const float*)d_in[0];
    const float* Win  = (const float*)d_in[1];
    const float* bin  = (const float*)d_in[2];
    const float* Ws   = (const float*)d_in[3];
    const float* bs   = (const float*)d_in[4];
    const float* Wout = (const float*)d_in[5];
    const float* bout = (const float*)d_in[6];
    float* out = (float*)d_out;

    char* ws = (char*)d_ws;
    _Float16* wsh  = (_Float16*)ws;
    _Float16* w0sh = wsh + WSH_HALVES;
    float* bpad  = (float*)(ws + OFF_BPAD_B);
    float* woutp = (float*)(ws + OFF_WOUT_B);

    hipLaunchKernelGGL(actor_prep, dim3((TOTAL_PREP + 255) / 256), dim3(256), 0, stream,
                       Win, bin, Ws, bs, Wout, wsh, w0sh, bpad, woutp);

    const int nrows = in_sizes[0] / DIN;   // 65536
    hipLaunchKernelGGL(actor_main, dim3(nrows / ROWS), dim3(128), 0, stream,
                       x, wsh, w0sh, bpad, woutp, bout, out);
}

// Round 17
// 255.834 us; speedup vs baseline: 1.0844x; 1.0350x over previous
//
#include <hip/hip_runtime.h>
#include <cmath>

// ---------------- problem constants ----------------
#define NLAYERS 100      // hidden layers (scan)
#define DIN     64       // input features
#define WDIM    100      // hidden width
#define NTT     4        // 4 n-tiles of 32 (128 neuron cols; bias col = 100)
#define NTW     2        // n-tiles per wave (wave w owns nt = 2w, 2w+1)
#define RT      2        // two 32-row tiles -> 64 rows per block
#define ROWS    64
#define KS      7        // 7 k-steps of 16 -> K=112 (useful 101)
#define PSTR    136      // f16 h row stride (272 B, b128-aligned)
#define BUF     (64 * PSTR)   // one 64-row h buffer in halves

typedef _Float16 half8  __attribute__((ext_vector_type(8)));
typedef _Float16 half2v __attribute__((ext_vector_type(2)));
typedef __fp16   fp16x2 __attribute__((ext_vector_type(2)));
typedef float    f32x4  __attribute__((ext_vector_type(4)));
typedef float    f32x16 __attribute__((ext_vector_type(16)));

// ---------------- workspace layout ----------------
// wsh: [l][ks7][nt4][lane][8] — frag stride 512 halves (1024 B).
// A-frag (32x32x16, operand-swapped W^T): lane -> neuron n = nt*32+(lane&31);
// elem j -> k = ks*16 + (lane>>5)*8 + j.
//   k<100 && n<100   -> Ws[l][k][n]
//   k==100 && n<100  -> bs[l][n]      (bias row vs h col 100 == 1.0)
//   k==100 && n==100 -> 1.0           (bias col self-sustains)
#define WSH_LAYER_HALVES (KS * NTT * 64 * 8)             // 14336
#define WSH_HALVES       (NLAYERS * WSH_LAYER_HALVES)    // 1,433,600
#define W0_HALVES        (4 * NTT * 64 * 8)              // 8192 (input, K=64 = 4 ks)
#define BPAD_FLOATS      128                             // b_in padded; col 100 = 1.0
#define OFF_BPAD_B       ((WSH_HALVES + W0_HALVES) * 2)
#define OFF_WOUT_B       (OFF_BPAD_B + BPAD_FLOATS * 4)
#define WOUT_FLOATS      128
#define TOTAL_PREP       (WSH_HALVES + W0_HALVES + BPAD_FLOATS + WOUT_FLOATS)

__global__ void actor_prep(const float* __restrict__ Win, const float* __restrict__ bin,
                           const float* __restrict__ Ws,  const float* __restrict__ bs,
                           const float* __restrict__ Wout,
                           _Float16* __restrict__ wsh, _Float16* __restrict__ w0sh,
                           float* __restrict__ bpad, float* __restrict__ woutp) {
    int t = blockIdx.x * 256 + threadIdx.x;
    if (t < WSH_HALVES) {                       // hidden-layer weights
        int j    = t & 7;
        int lane = (t >> 3) & 63;
        int fid  = t >> 9;                      // (l*7 + ks)*4 + nt
        int nt   = fid & 3;
        int r2   = fid >> 2;
        int ks   = r2 % 7;
        int l    = r2 / 7;
        int k = ks * 16 + (lane >> 5) * 8 + j;
        int n = nt * 32 + (lane & 31);
        float v = 0.f;
        if (k < WDIM && n < WDIM)            v = Ws[(l * WDIM + k) * WDIM + n];
        else if (k == 100 && n < WDIM)       v = bs[l * WDIM + n];   // bias row
        else if (k == 100 && n == 100)       v = 1.0f;               // keep bias col alive
        wsh[t] = (_Float16)v;
        return;
    }
    int t2 = t - WSH_HALVES;
    if (t2 < W0_HALVES) {                       // input layer (K=64)
        int j    = t2 & 7;
        int lane = (t2 >> 3) & 63;
        int fid  = t2 >> 9;                     // ks*4 + nt
        int nt   = fid & 3;
        int ks   = fid >> 2;
        int k = ks * 16 + (lane >> 5) * 8 + j;  // < 64
        int n = nt * 32 + (lane & 31);
        float v = (n < WDIM) ? Win[k * WDIM + n] : 0.f;
        w0sh[t2] = (_Float16)v;
        return;
    }
    int t3 = t2 - WSH_HALVES >= 0 ? t2 - W0_HALVES : 0;   // (guard unused)
    t3 = t2 - W0_HALVES;
    if (t3 < BPAD_FLOATS) {                     // padded b_in; col 100 = 1.0 seed
        float v = (t3 < WDIM) ? bin[t3] : (t3 == 100 ? 1.0f : 0.f);
        bpad[t3] = v;
        return;
    }
    int t4 = t3 - BPAD_FLOATS;
    if (t4 < WOUT_FLOATS) woutp[t4] = (t4 < WDIM) ? Wout[t4] : 0.f;
}

// split fp32 -> hi/lo fp16 (layer-0 input only: keep input fidelity)
__device__ __forceinline__ void split8(const float* __restrict__ p, half8& hi, half8& lo) {
    f32x4 u0 = *(const f32x4*)p;
    f32x4 u1 = *(const f32x4*)(p + 4);
    float v[8] = {u0[0], u0[1], u0[2], u0[3], u1[0], u1[1], u1[2], u1[3]};
#pragma unroll
    for (int e = 0; e < 8; e += 2) {
        fp16x2 h = __builtin_amdgcn_cvt_pkrtz(v[e], v[e + 1]);
        float r0 = v[e]     - (float)h[0];
        float r1 = v[e + 1] - (float)h[1];
        fp16x2 l = __builtin_amdgcn_cvt_pkrtz(r0, r1);
        hi[e] = (_Float16)h[0]; hi[e + 1] = (_Float16)h[1];
        lo[e] = (_Float16)l[0]; lo[e + 1] = (_Float16)l[1];
    }
}

// epilogue one QUAD (regs 4qd..4qd+3 of a 32x32 C = 4 contiguous neurons):
// RNE f16 cvt, packed-f16 leaky, one b64 store
__device__ __forceinline__ void ep_quad(const f32x16 a, int qd, _Float16* __restrict__ d) {
    half2v p01, p23;
    p01[0] = (_Float16)a[4 * qd + 0]; p01[1] = (_Float16)a[4 * qd + 1];
    p23[0] = (_Float16)a[4 * qd + 2]; p23[1] = (_Float16)a[4 * qd + 3];
    const half2v slope = {(_Float16)0.01f, (_Float16)0.01f};
    p01 = __builtin_elementwise_max(p01, p01 * slope);
    p23 = __builtin_elementwise_max(p23, p23 * slope);
    uint2 w;
    w.x = __builtin_bit_cast(unsigned, p01);
    w.y = __builtin_bit_cast(unsigned, p23);
    *reinterpret_cast<uint2*>(d) = w;
}

// ============================================================
// Main: 128-thread blocks (2 waves), 64 rows, 32x32x16 MFMA, K=112.
// r17 vs r16: rt-level chunks with the TWO ntl accumulator chains
// INTERLEAVED — r16's per-chunk single chain was 7 dependent MFMAs
// back-to-back (dependent MFMA latency > issue: m119 needed 2-8
// independent chains for peak). Chunk rt1 hides epi(rt0,this layer)
// + W(L+1) refill; tail = epi(rt1) + barrier.
// C/D layout (HW-verified m74/m101): col(batch)=lane&31,
// row(neuron)=(reg&3)+8*(reg>>2)+4*(lane>>5). N-split: wave w owns
// nt {2w,2w+1}. h in LDS double-buffered by layer parity, 1
// barrier/layer. HI-ONLY f16 activations (absmax 0.094, r8-r16).
// ============================================================
__global__ __launch_bounds__(128, 2)
void actor_main(const float* __restrict__ x,
                const _Float16* __restrict__ wsh,
                const _Float16* __restrict__ w0sh,
                const float* __restrict__ bpad,
                const float* __restrict__ woutp,
                const float* __restrict__ bout,
                float* __restrict__ out) {
    __shared__ _Float16 hp[2 * BUF];     // two 64-row h buffers (layer parity)
    const int lane = threadIdx.x & 63;
    const int wid  = threadIdx.x >> 6;   // 0,1: owns nt {2w, 2w+1}
    const int g = lane >> 5, b31 = lane & 31;
    const int rowbase = blockIdx.x * ROWS;
    const int ntb = wid * NTW;

    f32x16 acc[RT][NTW];
    half8 wb[KS][NTW];                   // my W frags for the whole layer
    const f32x16 zero16 = {0,0,0,0, 0,0,0,0, 0,0,0,0, 0,0,0,0};

    // ---- input layer (K=64 = 4 k-steps of 16) ----
    half8 w0[4][NTW];
#pragma unroll
    for (int ks = 0; ks < 4; ++ks)
#pragma unroll
        for (int ntl = 0; ntl < NTW; ++ntl)
            w0[ks][ntl] = *(const half8*)(w0sh + (ks * NTT + ntb + ntl) * 512 + lane * 8);
#pragma unroll
    for (int rt = 0; rt < RT; ++rt)
#pragma unroll
        for (int ntl = 0; ntl < NTW; ++ntl)
#pragma unroll
            for (int qd = 0; qd < 4; ++qd) {
                f32x4 tq = *(const f32x4*)(bpad + (ntb + ntl) * 32 + 8 * qd + 4 * g);
#pragma unroll
                for (int r = 0; r < 4; ++r) acc[rt][ntl][4 * qd + r] = tq[r];
            }
#pragma unroll
    for (int rt = 0; rt < RT; ++rt) {
        const float* xr = x + (rowbase + rt * 32 + b31) * DIN;
#pragma unroll
        for (int ks = 0; ks < 4; ++ks) {
            half8 xhi, xlo;
            split8(xr + ks * 16 + g * 8, xhi, xlo);
#pragma unroll
            for (int ntl = 0; ntl < NTW; ++ntl) {
                acc[rt][ntl] = __builtin_amdgcn_mfma_f32_32x32x16_f16(w0[ks][ntl], xhi, acc[rt][ntl], 0, 0, 0);
                acc[rt][ntl] = __builtin_amdgcn_mfma_f32_32x32x16_f16(w0[ks][ntl], xlo, acc[rt][ntl], 0, 0, 0);
            }
        }
    }
    // epi0 -> buffer 0; prefetch W(0)
#pragma unroll
    for (int rt = 0; rt < RT; ++rt)
#pragma unroll
        for (int ntl = 0; ntl < NTW; ++ntl) {
            _Float16* d = hp + (rt * 32 + b31) * PSTR + (ntb + ntl) * 32 + 4 * g;
#pragma unroll
            for (int qd = 0; qd < 4; ++qd) ep_quad(acc[rt][ntl], qd, d + 8 * qd);
        }
#pragma unroll
    for (int ks = 0; ks < KS; ++ks)
#pragma unroll
        for (int ntl = 0; ntl < NTW; ++ntl)
            wb[ks][ntl] = *(const half8*)(wsh + (ks * NTT + ntb + ntl) * 512 + lane * 8);
    __syncthreads();

    // ---------------- 100 hidden layers ----------------
    // layer l: reads buf[l&1] (h of l-1), writes buf[(l+1)&1]
#pragma unroll 1
    for (int l = 0; l < NLAYERS; ++l) {
        const _Float16* rb = hp + (l & 1) * BUF;
        _Float16* wbf = hp + ((l + 1) & 1) * BUF;
        const _Float16* wn = wsh + (l < NLAYERS - 1 ? l + 1 : l) * WSH_LAYER_HALVES;
        half8 bh[KS];

        // ---- chunk rt=0: 14 MFMAs as 2 interleaved chains (pure compute) ----
#pragma unroll
        for (int ks = 0; ks < KS; ++ks)
            bh[ks] = *(const half8*)(rb + b31 * PSTR + ks * 16 + g * 8);
#pragma unroll
        for (int ks = 0; ks < KS; ++ks) {
            acc[0][0] = __builtin_amdgcn_mfma_f32_32x32x16_f16(
                wb[ks][0], bh[ks], (ks == 0 ? zero16 : acc[0][0]), 0, 0, 0);
            acc[0][1] = __builtin_amdgcn_mfma_f32_32x32x16_f16(
                wb[ks][1], bh[ks], (ks == 0 ? zero16 : acc[0][1]), 0, 0, 0);
        }

        // ---- chunk rt=1: 2 chains || epi(rt0) || W(L+1) refill ----
#pragma unroll
        for (int ks = 0; ks < KS; ++ks)      // hoisted before epi writes (DS in-order)
            bh[ks] = *(const half8*)(rb + (32 + b31) * PSTR + ks * 16 + g * 8);
        _Float16* d00 = wbf + b31 * PSTR + (ntb + 0) * 32 + 4 * g;
        _Float16* d01 = wbf + b31 * PSTR + (ntb + 1) * 32 + 4 * g;
#pragma unroll
        for (int ks = 0; ks < KS; ++ks) {
            acc[1][0] = __builtin_amdgcn_mfma_f32_32x32x16_f16(
                wb[ks][0], bh[ks], (ks == 0 ? zero16 : acc[1][0]), 0, 0, 0);
            acc[1][1] = __builtin_amdgcn_mfma_f32_32x32x16_f16(
                wb[ks][1], bh[ks], (ks == 0 ? zero16 : acc[1][1]), 0, 0, 0);
            // wb[ks] dead after its rt1 mfmas: refill with W(L+1)[ks]
            wb[ks][0] = *(const half8*)(wn + (ks * NTT + ntb + 0) * 512 + lane * 8);
            wb[ks][1] = *(const half8*)(wn + (ks * NTT + ntb + 1) * 512 + lane * 8);
            if (ks < 4) {                    // epi of rt0 (this layer): 8 quads over 4 slots
                ep_quad(acc[0][0], ks, d00 + 8 * ks);
                ep_quad(acc[0][1], ks, d01 + 8 * ks);
            }
        }
        // tail: epi of rt1 (8 quads), then layer barrier
        {
            _Float16* d10 = wbf + (32 + b31) * PSTR + (ntb + 0) * 32 + 4 * g;
            _Float16* d11 = wbf + (32 + b31) * PSTR + (ntb + 1) * 32 + 4 * g;
#pragma unroll
            for (int qd = 0; qd < 4; ++qd) {
                ep_quad(acc[1][0], qd, d10 + 8 * qd);
                ep_quad(acc[1][1], qd, d11 + 8 * qd);
            }
        }
        __syncthreads();
    }
    // acc[rt][ntl] = pre-activation of layer 99 for my neurons (in regs)

    // ---------------- heads: leaky + dot(W_out), combine via LDS ----------------
    float part[RT];
#pragma unroll
    for (int rt = 0; rt < RT; ++rt) {
        float s = 0.f;
#pragma unroll
        for (int ntl = 0; ntl < NTW; ++ntl)
#pragma unroll
            for (int qd = 0; qd < 4; ++qd) {
                f32x4 w4 = *(const f32x4*)(woutp + (ntb + ntl) * 32 + 8 * qd + 4 * g);
#pragma unroll
                for (int r = 0; r < 4; ++r) {
                    float a = acc[rt][ntl][4 * qd + r];
                    float v = fmaxf(a, 0.01f * a);
                    s += v * w4[r];
                }
            }
        s += __shfl_xor(s, 32);              // combine the two k-groups (same batch col)
        part[rt] = s;
    }
    float* red = (float*)hp;                 // scratch (final barrier already passed)
#pragma unroll
    for (int rt = 0; rt < RT; ++rt)
        if (lane < 32) red[wid * 64 + rt * 32 + b31] = part[rt];
    __syncthreads();
    {
        const int r = threadIdx.x;
        if (r < 64) {
            float tot = red[r] + red[64 + r] + bout[0];
            out[rowbase + r] = tanhf(tot) * 4.5f + 5.5f;   // (tanh+1)/2*9 + 1
        }
    }
}

extern "C" void kernel_launch(void* const* d_in, const int* in_sizes, int n_in,
                              void* d_out, int out_size, void* d_ws, size_t ws_size,
                              hipStream_t stream) {
    const float* x    = (const float*)d_in[0];
    const float* Win  = (const float*)d_in[1];
    const float* bin  = (const float*)d_in[2];
    const float* Ws   = (const float*)d_in[3];
    const float* bs   = (const float*)d_in[4];
    const float* Wout = (const float*)d_in[5];
    const float* bout = (const float*)d_in[6];
    float* out = (float*)d_out;

    char* ws = (char*)d_ws;
    _Float16* wsh  = (_Float16*)ws;
    _Float16* w0sh = wsh + WSH_HALVES;
    float* bpad  = (float*)(ws + OFF_BPAD_B);
    float* woutp = (float*)(ws + OFF_WOUT_B);

    hipLaunchKernelGGL(actor_prep, dim3((TOTAL_PREP + 255) / 256), dim3(256), 0, stream,
                       Win, bin, Ws, bs, Wout, wsh, w0sh, bpad, woutp);

    const int nrows = in_sizes[0] / DIN;   // 65536
    hipLaunchKernelGGL(actor_main, dim3(nrows / ROWS), dim3(128), 0, stream,
                       x, wsh, w0sh, bpad, woutp, bout, out);
}